// Round 1
// baseline (319.504 us; speedup 1.0000x reference)
//
#include <hip/hip_runtime.h>

// NormalizationLayer: out = (v, exp(-adj^2 * c)), c = 1/(2*(100*sigmoid(s)+1e-5)^2),
// s = (v W1^T)(v W2^T)^T = v (W1^T W2) v^T = (v M) v^T.
//
// R5 = R4 + adj register-prefetch (T14 async-stage split):
//   - first 8 adj rows/thread issued at kernel entry (pinned with a compiler
//     memory barrier so they can't sink past the K-loop) -> HBM read stream
//     is in flight during the GEMM phase instead of serial after it.
//   - remaining 8 rows issued right after the p-tile store (acc regs dead,
//     stays under the 128-VGPR / 4-blocks-per-CU budget).
//   - iter-0 top barrier elided (unrolled K-loop) so staging loads issue
//     before the prefetch drain.

typedef _Float16 half8_t __attribute__((ext_vector_type(8)));
typedef _Float16 half4_t __attribute__((ext_vector_type(4)));
typedef float floatx4 __attribute__((ext_vector_type(4)));

#define LDSS 72   // K-loop LDS row stride in f16 (144 B, b128-aligned)
#define PS   132  // p-tile row stride in f16 (264 B, banks balanced)

// ---------------- kernel 1: copy v -> out0, convert v -> f16 ----------------
__global__ void prep_kernel(const floatx4* __restrict__ v4,
                            floatx4* __restrict__ out4,
                            half4_t* __restrict__ vf4) {
    int idx = blockIdx.x * 256 + threadIdx.x;   // 4096*256 = 4194304/4 exact
    floatx4 t = v4[idx];
    out4[idx] = t;
    half4_t h;
    h[0] = (_Float16)t[0]; h[1] = (_Float16)t[1];
    h[2] = (_Float16)t[2]; h[3] = (_Float16)t[3];
    vf4[idx] = h;
}

// ---------------- kernel 2: Mt[j][i] = sum_o W2[o][j] * W1[o][i] ----------------
__global__ void mt_kernel(const float* __restrict__ W1,
                          const float* __restrict__ W2,
                          _Float16* __restrict__ Mt) {
    __shared__ float w2col[256];
    const int j = blockIdx.x;
    const int i = threadIdx.x;
    w2col[i] = W2[i * 256 + j];
    __syncthreads();
    float acc = 0.f;
    #pragma unroll 8
    for (int o = 0; o < 256; ++o)
        acc += w2col[o] * W1[o * 256 + i];
    Mt[j * 256 + i] = (_Float16)acc;
}

// ---------------- GEMM: C[m][n] = sum_k A[m,k]*Bm[n,k], K=256, tile 128x128 ----
// MFMA operand roles: A-op = n-frag, B-op = m-frag => D: n = quad*4+reg, m = l16.
// MODE 0: store half4 u-tile. MODE 1: p -> LDS, then coalesced streaming epilogue.
template<int MODE>
__global__ __launch_bounds__(256, 4)
void gemm_kernel(const _Float16* __restrict__ A, const _Float16* __restrict__ Bm,
                 size_t a_bstride, size_t b_bstride,
                 _Float16* __restrict__ Uout,
                 const float* __restrict__ adj, float* __restrict__ out) {
    __shared__ _Float16 smem[2 * 128 * LDSS];   // As | Bs ; reused as p-tile (128*PS)
    _Float16* As = smem;
    _Float16* Bs = smem + 128 * LDSS;

    const int tid  = threadIdx.x;
    const int lane = tid & 63;
    const int wid  = tid >> 6;
    const int wm   = wid >> 1;          // 2x2 wave grid, each wave 64(m)x64(n)
    const int wn   = wid & 1;
    const int quad = lane >> 4;
    const int l16  = lane & 15;

    const int m0 = blockIdx.x * 128;
    const int n0 = blockIdx.y * 128;
    const int batch = blockIdx.z;

    const _Float16* Ab = A  + (size_t)batch * a_bstride;
    const _Float16* Bb = Bm + (size_t)batch * b_bstride;

    // ---- epilogue addressing + adj prefetch (MODE 1) ----
    const int srow = tid >> 5;            // 0..7
    const int scol = (tid & 31) * 4;
    const size_t gbase = (size_t)batch * 2048 * 2048
                       + (size_t)m0 * 2048 + n0 + scol;

    floatx4 aj0[8];
    if (MODE == 1) {
        // Issue first half of this block's adj tile NOW: the read stream is
        // in flight on HBM while the K-loop runs off L2-resident vf/uf.
        #pragma unroll
        for (int p = 0; p < 8; ++p)
            aj0[p] = *(const floatx4*)(adj + gbase + (size_t)(p * 8 + srow) * 2048);
        asm volatile("" ::: "memory");    // pin issue point: no sinking past K-loop
    }

    floatx4 acc[4][4];   // acc[i][j]: i -> n-frag, j -> m-frag
    #pragma unroll
    for (int i = 0; i < 4; ++i)
        #pragma unroll
        for (int j = 0; j < 4; ++j)
            acc[i][j] = (floatx4){0.f, 0.f, 0.f, 0.f};

    const int rrow = tid >> 3;          // staging: 8 threads (8x16B) per 64-col row
    const int ch8  = (tid & 7) * 8;

    #pragma unroll
    for (int kc = 0; kc < 256; kc += 64) {
        if (kc) __syncthreads();        // iter-0 barrier elided (LDS not yet read)
        #pragma unroll
        for (int r = 0; r < 4; ++r) {
            int row = r * 32 + rrow;
            uint4 va = *(const uint4*)(Ab + (((size_t)(m0 + row)) << 8) + kc + ch8);
            uint4 vb = *(const uint4*)(Bb + (((size_t)(n0 + row)) << 8) + kc + ch8);
            *(uint4*)(&As[row * LDSS + ch8]) = va;
            *(uint4*)(&Bs[row * LDSS + ch8]) = vb;
        }
        __syncthreads();
        #pragma unroll
        for (int ks = 0; ks < 2; ++ks) {
            const int kof = ks * 32 + quad * 8;   // operand layout: [row=lane&15][k=quad*8+j]
            half8_t mf[4], nf[4];
            #pragma unroll
            for (int t = 0; t < 4; ++t) {
                mf[t] = *(const half8_t*)(&As[(wm * 64 + t * 16 + l16) * LDSS + kof]);
                nf[t] = *(const half8_t*)(&Bs[(wn * 64 + t * 16 + l16) * LDSS + kof]);
            }
            #pragma unroll
            for (int i = 0; i < 4; ++i)
                #pragma unroll
                for (int j = 0; j < 4; ++j)
                    acc[i][j] = __builtin_amdgcn_mfma_f32_16x16x32_f16(
                        nf[i], mf[j], acc[i][j], 0, 0, 0);   // A-op = n, B-op = m
        }
    }

    if (MODE == 0) {
        // D layout: n = quad*4 + reg, m = l16
        #pragma unroll
        for (int j = 0; j < 4; ++j) {
            int m = m0 + wm * 64 + j * 16 + l16;        // u row
            #pragma unroll
            for (int i = 0; i < 4; ++i) {
                int n = wn * 64 + i * 16 + quad * 4;    // u col (grid.y covers n0)
                half4_t h;
                #pragma unroll
                for (int r = 0; r < 4; ++r) h[r] = (_Float16)acc[i][j][r];
                *(half4_t*)(Uout + (size_t)m * 256 + n0 + n) = h;
            }
        }
    } else {
        // Phase 1: p = 100*sigmoid(s) + 1e-5 -> f16 LDS tile (layout transform)
        __syncthreads();                      // all waves done reading As/Bs
        _Float16* Ps = smem;                  // 128 * PS * 2 = 33792 B <= 36864 B
        #pragma unroll
        for (int j = 0; j < 4; ++j) {
            int ml = wm * 64 + j * 16 + l16;
            #pragma unroll
            for (int i = 0; i < 4; ++i) {
                int nl = wn * 64 + i * 16 + quad * 4;
                half4_t h;
                #pragma unroll
                for (int r = 0; r < 4; ++r) {
                    float s = acc[i][j][r];
                    float p = 100.0f / (1.0f + __expf(-s)) + 1e-5f;
                    h[r] = (_Float16)p;
                }
                *(half4_t*)(&Ps[ml * PS + nl]) = h;
            }
        }

        // Issue second half of adj tile: acc is dead here, so this fits in the
        // freed registers; latency hides under the barrier + passes 0-7.
        floatx4 aj1[8];
        #pragma unroll
        for (int p = 0; p < 8; ++p)
            aj1[p] = *(const floatx4*)(adj + gbase + (size_t)((p + 8) * 8 + srow) * 2048);
        asm volatile("" ::: "memory");

        __syncthreads();

        // Phase 2: fully-coalesced streaming epilogue, all adj already in regs.
        #pragma unroll
        for (int pass = 0; pass < 8; ++pass) {
            int r = pass * 8 + srow;
            size_t g = gbase + (size_t)r * 2048;
            floatx4 a = aj0[pass];
            half4_t ph = *(const half4_t*)(&Ps[r * PS + scol]);
            floatx4 o;
            #pragma unroll
            for (int e = 0; e < 4; ++e) {
                float ip = __builtin_amdgcn_rcpf((float)ph[e]);
                float q = a[e] * ip;
                o[e] = __expf(-0.5f * q * q);
            }
            __builtin_nontemporal_store(o, (floatx4*)(out + g));
        }
        #pragma unroll
        for (int pass = 8; pass < 16; ++pass) {
            int r = pass * 8 + srow;
            size_t g = gbase + (size_t)r * 2048;
            floatx4 a = aj1[pass - 8];
            half4_t ph = *(const half4_t*)(&Ps[r * PS + scol]);
            floatx4 o;
            #pragma unroll
            for (int e = 0; e < 4; ++e) {
                float ip = __builtin_amdgcn_rcpf((float)ph[e]);
                float q = a[e] * ip;
                o[e] = __expf(-0.5f * q * q);
            }
            __builtin_nontemporal_store(o, (floatx4*)(out + g));
        }
    }
}

extern "C" void kernel_launch(void* const* d_in, const int* in_sizes, int n_in,
                              void* d_out, int out_size, void* d_ws, size_t ws_size,
                              hipStream_t stream) {
    const float* v   = (const float*)d_in[0];   // [8,2048,256]
    const float* adj = (const float*)d_in[1];   // [8,2048,2048]
    const float* W1  = (const float*)d_in[2];   // [256,256]
    const float* W2  = (const float*)d_in[3];   // [256,256]

    float* out_v   = (float*)d_out;                              // output 0: v copy
    float* out_adj = (float*)d_out + (size_t)8 * 2048 * 256;     // output 1

    char* ws = (char*)d_ws;
    _Float16* vf = (_Float16*)ws;                          // 8 MiB  [8*2048,256] f16
    _Float16* uf = (_Float16*)(ws + ((size_t)8 << 20));    // 8 MiB  [8*2048,256] f16
    _Float16* Mt = (_Float16*)(ws + ((size_t)16 << 20));   // 128 KiB [256,256] f16 (M^T)

    prep_kernel<<<4096, 256, 0, stream>>>((const floatx4*)v, (floatx4*)out_v, (half4_t*)vf);
    mt_kernel<<<256, 256, 0, stream>>>(W1, W2, Mt);
    // u = v * M : A rows = 16384 (all batches flat), Bm = Mt (256 rows)
    gemm_kernel<0><<<dim3(128, 2, 1), 256, 0, stream>>>(
        vf, Mt, 0, 0, uf, nullptr, nullptr);
    // s = u * v^T per batch + fused epilogue
    gemm_kernel<1><<<dim3(16, 16, 8), 256, 0, stream>>>(
        uf, vf, (size_t)2048 * 256, (size_t)2048 * 256, nullptr, adj, out_adj);
}

// Round 2
// 314.560 us; speedup vs baseline: 1.0157x; 1.0157x over previous
//
#include <hip/hip_runtime.h>

// NormalizationLayer: out = (v, exp(-adj^2 * c)), c = 1/(2*(100*sigmoid(s)+1e-5)^2),
// s = (v W1^T)(v W2^T)^T = v (W1^T W2) v^T = (v M) v^T.
//
// R6 = R5 prefetch mechanism + the registers to pay for it:
//   - R5 post-mortem: launch_bounds(256,4) caps unified regs at 128; acc(64 AGPR)
//     + K-loop frags already hit the cap, so aj0[8] (32 VGPR) spilled to scratch
//     (+90 MB HBM traffic). But HBM BW still rose 2.66->3.23 TB/s: the early-issue
//     mechanism works.
//   - Fix: __launch_bounds__(256,3) -> ~168-reg budget, prefetch stays in VGPRs.
//     3 blocks/CU (12 waves) instead of 4 (16): trade 25% TLP for 128 B/thread of
//     in-flight HBM reads covering the K-phase.
//   - adj loads are non-temporal: one-shot stream, don't evict L2-resident vf/uf.

typedef _Float16 half8_t __attribute__((ext_vector_type(8)));
typedef _Float16 half4_t __attribute__((ext_vector_type(4)));
typedef float floatx4 __attribute__((ext_vector_type(4)));

#define LDSS 72   // K-loop LDS row stride in f16 (144 B, b128-aligned)
#define PS   132  // p-tile row stride in f16 (264 B, banks balanced)

// ---------------- kernel 1: copy v -> out0, convert v -> f16 ----------------
__global__ void prep_kernel(const floatx4* __restrict__ v4,
                            floatx4* __restrict__ out4,
                            half4_t* __restrict__ vf4) {
    int idx = blockIdx.x * 256 + threadIdx.x;   // 4096*256 = 4194304/4 exact
    floatx4 t = v4[idx];
    out4[idx] = t;
    half4_t h;
    h[0] = (_Float16)t[0]; h[1] = (_Float16)t[1];
    h[2] = (_Float16)t[2]; h[3] = (_Float16)t[3];
    vf4[idx] = h;
}

// ---------------- kernel 2: Mt[j][i] = sum_o W2[o][j] * W1[o][i] ----------------
__global__ void mt_kernel(const float* __restrict__ W1,
                          const float* __restrict__ W2,
                          _Float16* __restrict__ Mt) {
    __shared__ float w2col[256];
    const int j = blockIdx.x;
    const int i = threadIdx.x;
    w2col[i] = W2[i * 256 + j];
    __syncthreads();
    float acc = 0.f;
    #pragma unroll 8
    for (int o = 0; o < 256; ++o)
        acc += w2col[o] * W1[o * 256 + i];
    Mt[j * 256 + i] = (_Float16)acc;
}

// ---------------- GEMM: C[m][n] = sum_k A[m,k]*Bm[n,k], K=256, tile 128x128 ----
// MFMA operand roles: A-op = n-frag, B-op = m-frag => D: n = quad*4+reg, m = l16.
// MODE 0: store half4 u-tile. MODE 1: p -> LDS, then coalesced streaming epilogue.
template<int MODE>
__global__ __launch_bounds__(256, 3)
void gemm_kernel(const _Float16* __restrict__ A, const _Float16* __restrict__ Bm,
                 size_t a_bstride, size_t b_bstride,
                 _Float16* __restrict__ Uout,
                 const float* __restrict__ adj, float* __restrict__ out) {
    __shared__ _Float16 smem[2 * 128 * LDSS];   // As | Bs ; reused as p-tile (128*PS)
    _Float16* As = smem;
    _Float16* Bs = smem + 128 * LDSS;

    const int tid  = threadIdx.x;
    const int lane = tid & 63;
    const int wid  = tid >> 6;
    const int wm   = wid >> 1;          // 2x2 wave grid, each wave 64(m)x64(n)
    const int wn   = wid & 1;
    const int quad = lane >> 4;
    const int l16  = lane & 15;

    const int m0 = blockIdx.x * 128;
    const int n0 = blockIdx.y * 128;
    const int batch = blockIdx.z;

    const _Float16* Ab = A  + (size_t)batch * a_bstride;
    const _Float16* Bb = Bm + (size_t)batch * b_bstride;

    // ---- epilogue addressing + adj prefetch (MODE 1) ----
    const int srow = tid >> 5;            // 0..7
    const int scol = (tid & 31) * 4;
    const size_t gbase = (size_t)batch * 2048 * 2048
                       + (size_t)m0 * 2048 + n0 + scol;

    floatx4 aj0[8];
    if (MODE == 1) {
        // Issue first half of this block's adj tile NOW: the read stream is
        // in flight on HBM while the K-loop runs off L2-resident vf/uf.
        // launch_bounds(256,3) gives the 32 VGPRs to hold these without spill.
        #pragma unroll
        for (int p = 0; p < 8; ++p)
            aj0[p] = __builtin_nontemporal_load(
                (const floatx4*)(adj + gbase + (size_t)(p * 8 + srow) * 2048));
        asm volatile("" ::: "memory");    // pin issue point: no sinking past K-loop
    }

    floatx4 acc[4][4];   // acc[i][j]: i -> n-frag, j -> m-frag
    #pragma unroll
    for (int i = 0; i < 4; ++i)
        #pragma unroll
        for (int j = 0; j < 4; ++j)
            acc[i][j] = (floatx4){0.f, 0.f, 0.f, 0.f};

    const int rrow = tid >> 3;          // staging: 8 threads (8x16B) per 64-col row
    const int ch8  = (tid & 7) * 8;

    #pragma unroll
    for (int kc = 0; kc < 256; kc += 64) {
        if (kc) __syncthreads();        // iter-0 barrier elided (LDS not yet read)
        #pragma unroll
        for (int r = 0; r < 4; ++r) {
            int row = r * 32 + rrow;
            uint4 va = *(const uint4*)(Ab + (((size_t)(m0 + row)) << 8) + kc + ch8);
            uint4 vb = *(const uint4*)(Bb + (((size_t)(n0 + row)) << 8) + kc + ch8);
            *(uint4*)(&As[row * LDSS + ch8]) = va;
            *(uint4*)(&Bs[row * LDSS + ch8]) = vb;
        }
        __syncthreads();
        #pragma unroll
        for (int ks = 0; ks < 2; ++ks) {
            const int kof = ks * 32 + quad * 8;   // operand layout: [row=lane&15][k=quad*8+j]
            half8_t mf[4], nf[4];
            #pragma unroll
            for (int t = 0; t < 4; ++t) {
                mf[t] = *(const half8_t*)(&As[(wm * 64 + t * 16 + l16) * LDSS + kof]);
                nf[t] = *(const half8_t*)(&Bs[(wn * 64 + t * 16 + l16) * LDSS + kof]);
            }
            #pragma unroll
            for (int i = 0; i < 4; ++i)
                #pragma unroll
                for (int j = 0; j < 4; ++j)
                    acc[i][j] = __builtin_amdgcn_mfma_f32_16x16x32_f16(
                        nf[i], mf[j], acc[i][j], 0, 0, 0);   // A-op = n, B-op = m
        }
    }

    if (MODE == 0) {
        // D layout: n = quad*4 + reg, m = l16
        #pragma unroll
        for (int j = 0; j < 4; ++j) {
            int m = m0 + wm * 64 + j * 16 + l16;        // u row
            #pragma unroll
            for (int i = 0; i < 4; ++i) {
                int n = wn * 64 + i * 16 + quad * 4;    // u col (grid.y covers n0)
                half4_t h;
                #pragma unroll
                for (int r = 0; r < 4; ++r) h[r] = (_Float16)acc[i][j][r];
                *(half4_t*)(Uout + (size_t)m * 256 + n0 + n) = h;
            }
        }
    } else {
        // Phase 1: p = 100*sigmoid(s) + 1e-5 -> f16 LDS tile (layout transform)
        __syncthreads();                      // all waves done reading As/Bs
        _Float16* Ps = smem;                  // 128 * PS * 2 = 33792 B <= 36864 B
        #pragma unroll
        for (int j = 0; j < 4; ++j) {
            int ml = wm * 64 + j * 16 + l16;
            #pragma unroll
            for (int i = 0; i < 4; ++i) {
                int nl = wn * 64 + i * 16 + quad * 4;
                half4_t h;
                #pragma unroll
                for (int r = 0; r < 4; ++r) {
                    float s = acc[i][j][r];
                    float p = 100.0f / (1.0f + __expf(-s)) + 1e-5f;
                    h[r] = (_Float16)p;
                }
                *(half4_t*)(&Ps[ml * PS + nl]) = h;
            }
        }

        // Issue second half of adj tile: acc is dead here, so this fits in the
        // freed registers; latency hides under the barrier + passes 0-7.
        floatx4 aj1[8];
        #pragma unroll
        for (int p = 0; p < 8; ++p)
            aj1[p] = __builtin_nontemporal_load(
                (const floatx4*)(adj + gbase + (size_t)((p + 8) * 8 + srow) * 2048));
        asm volatile("" ::: "memory");

        __syncthreads();

        // Phase 2: fully-coalesced streaming epilogue, all adj already in regs.
        #pragma unroll
        for (int pass = 0; pass < 8; ++pass) {
            int r = pass * 8 + srow;
            size_t g = gbase + (size_t)r * 2048;
            floatx4 a = aj0[pass];
            half4_t ph = *(const half4_t*)(&Ps[r * PS + scol]);
            floatx4 o;
            #pragma unroll
            for (int e = 0; e < 4; ++e) {
                float ip = __builtin_amdgcn_rcpf((float)ph[e]);
                float q = a[e] * ip;
                o[e] = __expf(-0.5f * q * q);
            }
            __builtin_nontemporal_store(o, (floatx4*)(out + g));
        }
        #pragma unroll
        for (int pass = 8; pass < 16; ++pass) {
            int r = pass * 8 + srow;
            size_t g = gbase + (size_t)r * 2048;
            floatx4 a = aj1[pass - 8];
            half4_t ph = *(const half4_t*)(&Ps[r * PS + scol]);
            floatx4 o;
            #pragma unroll
            for (int e = 0; e < 4; ++e) {
                float ip = __builtin_amdgcn_rcpf((float)ph[e]);
                float q = a[e] * ip;
                o[e] = __expf(-0.5f * q * q);
            }
            __builtin_nontemporal_store(o, (floatx4*)(out + g));
        }
    }
}

extern "C" void kernel_launch(void* const* d_in, const int* in_sizes, int n_in,
                              void* d_out, int out_size, void* d_ws, size_t ws_size,
                              hipStream_t stream) {
    const float* v   = (const float*)d_in[0];   // [8,2048,256]
    const float* adj = (const float*)d_in[1];   // [8,2048,2048]
    const float* W1  = (const float*)d_in[2];   // [256,256]
    const float* W2  = (const float*)d_in[3];   // [256,256]

    float* out_v   = (float*)d_out;                              // output 0: v copy
    float* out_adj = (float*)d_out + (size_t)8 * 2048 * 256;     // output 1

    char* ws = (char*)d_ws;
    _Float16* vf = (_Float16*)ws;                          // 8 MiB  [8*2048,256] f16
    _Float16* uf = (_Float16*)(ws + ((size_t)8 << 20));    // 8 MiB  [8*2048,256] f16
    _Float16* Mt = (_Float16*)(ws + ((size_t)16 << 20));   // 128 KiB [256,256] f16 (M^T)

    prep_kernel<<<4096, 256, 0, stream>>>((const floatx4*)v, (floatx4*)out_v, (half4_t*)vf);
    mt_kernel<<<256, 256, 0, stream>>>(W1, W2, Mt);
    // u = v * M : A rows = 16384 (all batches flat), Bm = Mt (256 rows)
    gemm_kernel<0><<<dim3(128, 2, 1), 256, 0, stream>>>(
        vf, Mt, 0, 0, uf, nullptr, nullptr);
    // s = u * v^T per batch + fused epilogue
    gemm_kernel<1><<<dim3(16, 16, 8), 256, 0, stream>>>(
        uf, vf, (size_t)2048 * 256, (size_t)2048 * 256, nullptr, adj, out_adj);
}